// Round 11
// baseline (308.254 us; speedup 1.0000x reference)
//
#include <hip/hip_runtime.h>

#define NN 4096
#define NE 65536
#define ND 64
#define BCAP 44   // per-node bucket capacity (Poisson(16) tail @44 ~ 1e-9)

// ---- kA (256x256): dots + zero x_pooled + dual bucketed edge scatter ----
__global__ void kA_pre(const float* __restrict__ x, const int* __restrict__ ei,
                       const float* __restrict__ wrel, const float* __restrict__ wroot,
                       double* __restrict__ srel, double* __restrict__ sroot,
                       int* __restrict__ gcnt_d, int* __restrict__ gcnt_s,
                       unsigned short* __restrict__ gbuf_d, unsigned short* __restrict__ gbuf_s,
                       float* __restrict__ out) {
    int gtid = blockIdx.x * blockDim.x + threadIdx.x;   // 65536 threads
    int lane = threadIdx.x & 63;

    float4* o4 = (float4*)out;
    o4[gtid] = make_float4(0.f, 0.f, 0.f, 0.f);         // zero x_pooled base (1 MB)

    int gwave = gtid >> 6;                              // 1024 waves, 4 nodes each
    for (int node = gwave; node < NN; node += 1024) {
        double xv = (double)x[node * ND + lane];
        double pr = xv * (double)wrel[lane];
        double po = xv * (double)wroot[lane];
        for (int off = 32; off > 0; off >>= 1) {
            pr += __shfl_down(pr, off);
            po += __shfl_down(po, off);
        }
        if (lane == 0) { srel[node] = pr; sroot[node] = po; }
    }

    int s = ei[gtid], d = ei[NE + gtid];                // one edge per thread
    int pd = atomicAdd(&gcnt_d[d], 1);
    if (pd < BCAP) gbuf_d[d * BCAP + pd] = (unsigned short)s;   // in-edges by dst
    int ps = atomicAdd(&gcnt_s[s], 1);
    if (ps < BCAP) gbuf_s[s * BCAP + ps] = (unsigned short)d;   // out-edges by src
}

// ---- kB (1x1024): keys + counting-push dataflow fixpoint ----
// earlier(u,v) <=> kq(u) < kq(v), kq = (~mono_f32_score)<<12 | node (stable argsort ties).
// cnt[v] = #earlier in-nbrs. On resolve, v pushes along its pruned out-list:
// center: atomicMin(best[w], kq_v) + fence + atomicSub(cnt[w]); absorbed: sub only.
// v resolves at cnt<=0: best==~0 -> center else absorbed by best&0xFFF.
// LDS: [0,128K): incsr u16 (until round-0) -> cnt i32 [0,16K) | best u64 [16K,48K)
//      | out-lists u16 [48K,128K) (P ~= 32.7K entries).  wt2 ints @ 131008.
// aux [128K,160K): srel f64 (stage) -> skey u64 (STATIC key table). wt @ aux+20544.
__global__ void __launch_bounds__(1024) kB_contract(
        const double* __restrict__ srel, const double* __restrict__ sroot,
        const float* __restrict__ bptr, const int* __restrict__ gcnt_d,
        const unsigned short* __restrict__ gbuf_d, const int* __restrict__ gcnt_s,
        const unsigned short* __restrict__ gbuf_s,
        int* __restrict__ map_g, int* __restrict__ rem_g, int* __restrict__ relab_g,
        int* __restrict__ perm_a, int* __restrict__ nkeep_g) {
    __shared__ __align__(16) char buf[163840];
    unsigned short* incsr = (unsigned short*)buf;
    int* cntv = (int*)buf;                                    // [0,16K)
    unsigned long long* best = (unsigned long long*)(buf + 16384);  // [16K,48K)
    unsigned short* outl = (unsigned short*)(buf + 49152);    // [48K,128K): 40960 entries
    int* wt2 = (int*)(buf + 131008);
    char* aux = buf + 131072;
    double* srel_lds = (double*)aux;
    volatile unsigned long long* skey = (volatile unsigned long long*)aux;
    int* wt = (int*)(aux + 20544);
    int tid = threadIdx.x, lane = tid & 63, wv = tid >> 6;

    // ---- prefix of capped in-degrees -> row starts/ends in regs ----
    int4 d4 = ((const int4*)gcnt_d)[tid];
    int t0 = min(d4.x, BCAP), t1 = min(d4.y, BCAP);
    int t2 = min(d4.z, BCAP), t3 = min(d4.w, BCAP);
    int tot = t0 + t1 + t2 + t3;
    int inc = tot;
    for (int off = 1; off < 64; off <<= 1) {
        int v = __shfl_up(inc, off);
        if (lane >= off) inc += v;
    }
    if (lane == 63) wt[wv] = inc;
    __syncthreads();
    if (wv == 0 && lane < 16) {
        int v = wt[lane];
        for (int off = 1; off < 16; off <<= 1) {
            int u2 = __shfl_up(v, off);
            if (lane >= off) v += u2;
        }
        wt[lane] = v;
    }
    __syncthreads();
    int waveoff = (wv > 0) ? wt[wv - 1] : 0;
    int excl = waveoff + inc - tot;
    int rs4[4], re4[4];
    rs4[0] = excl; rs4[1] = excl + t0; rs4[2] = excl + t0 + t1; rs4[3] = excl + t0 + t1 + t2;
    re4[0] = rs4[1]; re4[1] = rs4[2]; re4[2] = rs4[3]; re4[3] = rs4[3] + t3;
    __syncthreads();   // wt reads done before srel staging overwrites aux

    // ---- gather dst-bucket rows -> compact LDS in-CSR ----
    for (int t = 0; t < 4; ++t) {
        int v = 4 * tid + t;
        const unsigned short* gp = gbuf_d + v * BCAP;
        int base = rs4[t], dg = re4[t] - rs4[t];
        int j = 0;
        for (; j + 4 <= dg; j += 4) {
            ushort4 q = *(const ushort4*)(gp + j);
            incsr[base + j] = q.x; incsr[base + j + 1] = q.y;
            incsr[base + j + 2] = q.z; incsr[base + j + 3] = q.w;
        }
        for (; j < dg; ++j) incsr[base + j] = gp[j];
    }

    // ---- stage srel into LDS ----
    {
        double2* sl2 = (double2*)aux;
        const double2* sg2 = (const double2*)srel;
        for (int i = tid; i < NN / 2; i += 1024) sl2[i] = sg2[i];
    }
    __syncthreads();

    // ---- agg row-gather + key computation (regs only) ----
    double bv = (double)bptr[0];
    unsigned long long pk4[4];
    for (int t = 0; t < 4; ++t) {
        int v = 4 * tid + t;
        double s = 0.0;
        for (int e = rs4[t]; e < re4[t]; ++e) s += srel_lds[(int)incsr[e]];
        double arg = s + sroot[v] + bv;
        float sc = tanhf((float)arg);                    // f32 saturation => ref ties
        unsigned m = __float_as_uint(sc);
        m = (m & 0x80000000u) ? ~m : (m | 0x80000000u);  // monotone ascending
        pk4[t] = ((unsigned long long)(~m) << 12) | (unsigned long long)v;   // kq
    }
    __syncthreads();   // srel_lds reads done before skey overwrites region

    for (int t = 0; t < 4; ++t) skey[4 * tid + t] = pk4[t] << 2;   // static key table
    __syncthreads();

    // ---- round 0: count earlier in-nbrs (cnt), detect self-loops ----
    int cnt4[4];
    unsigned centerm = 0, selfm = 0;
    for (int t = 0; t < 4; ++t) {
        int v = 4 * tid + t;
        int c = 0;
        for (int e = rs4[t]; e < re4[t]; ++e) {
            int u = (int)incsr[e];
            if (u == v) { selfm |= 1u << t; continue; }
            if ((skey[u] >> 2) < pk4[t]) ++c;
        }
        cnt4[t] = c;
    }
    __syncthreads();   // in-rows dead; [0,128K) region reusable

    // ---- out-list build, phase A: count pruned out-degrees ----
    int m4[4];
    for (int t = 0; t < 4; ++t) {
        int v = 4 * tid + t;
        int od = min(gcnt_s[v], BCAP);
        const unsigned short* gp = gbuf_s + v * BCAP;
        int m = 0;
        for (int j = 0; j < od; ++j) {
            int w = (int)gp[j];
            if (w == v) continue;
            if (pk4[t] < (skey[w] >> 2)) ++m;
        }
        m4[t] = m;
    }
    int tot2 = m4[0] + m4[1] + m4[2] + m4[3];
    int inc2 = tot2;
    for (int off = 1; off < 64; off <<= 1) {
        int v = __shfl_up(inc2, off);
        if (lane >= off) inc2 += v;
    }
    if (lane == 63) wt2[wv] = inc2;
    __syncthreads();
    if (wv == 0 && lane < 16) {
        int v = wt2[lane];
        for (int off = 1; off < 16; off <<= 1) {
            int u2 = __shfl_up(v, off);
            if (lane >= off) v += u2;
        }
        wt2[lane] = v;
    }
    __syncthreads();
    int woff = (wv > 0) ? wt2[wv - 1] : 0;
    int obase = woff + inc2 - tot2;
    int os4[4];
    os4[0] = obase; os4[1] = obase + m4[0];
    os4[2] = os4[1] + m4[1]; os4[3] = os4[2] + m4[2];

    // ---- phase B: write pruned out-lists (rows thread-private; L2-warm re-read) ----
    for (int t = 0; t < 4; ++t) {
        int v = 4 * tid + t;
        int od = min(gcnt_s[v], BCAP);
        const unsigned short* gp = gbuf_s + v * BCAP;
        int c = os4[t];
        for (int j = 0; j < od; ++j) {
            int w = (int)gp[j];
            if (w == v) continue;
            if (pk4[t] < (skey[w] >> 2)) outl[c++] = (unsigned short)w;
        }
    }
    // init cnt/best for own nodes
    for (int t = 0; t < 4; ++t) {
        int v = 4 * tid + t;
        cntv[v] = cnt4[t];
        best[v] = ~0ULL;
    }
    __syncthreads();

    // ---- counting-push dataflow fixpoint ----
    unsigned resolved = 0;
    int guard = 0;
    while (resolved != 0xFu && guard < 4000000) {
        ++guard;
        bool prog = false;
        for (int t = 0; t < 4; ++t) {
            if (resolved & (1u << t)) continue;
            int v = 4 * tid + t;
            if (*(volatile int*)(cntv + v) > 0) continue;
            unsigned long long bvv = *(volatile unsigned long long*)(best + v);
            int s0 = os4[t], s1 = os4[t] + m4[t];
            if (bvv == ~0ULL) {                       // center
                map_g[v] = v;
                centerm |= 1u << t;
                unsigned long long kq = pk4[t];
                for (int j = s0; j < s1; ++j) atomicMin(&best[(int)outl[j]], kq);
                __threadfence_block();                // mins visible before decrements
            } else {                                  // absorbed by min-key center
                map_g[v] = (int)(bvv & 0xFFFULL);
            }
            for (int j = s0; j < s1; ++j) atomicSub(&cntv[(int)outl[j]], 1);
            resolved |= 1u << t;
            prog = true;
        }
        if (!prog) __builtin_amdgcn_s_sleep(1);
    }
    __syncthreads();

    // ---- relabel prefix + perm + globals ----
    int remb[4], cnt4b = 0;
    for (int t = 0; t < 4; ++t) {
        remb[t] = ((centerm >> t) & 1) && !((selfm >> t) & 1);
        cnt4b += remb[t];
    }
    int inc3 = cnt4b;
    for (int off = 1; off < 64; off <<= 1) {
        int v = __shfl_up(inc3, off);
        if (lane >= off) inc3 += v;
    }
    if (lane == 63) wt[wv] = inc3;
    __syncthreads();
    if (wv == 0 && lane < 16) {
        int v = wt[lane];
        for (int off = 1; off < 16; off <<= 1) {
            int u2 = __shfl_up(v, off);
            if (lane >= off) v += u2;
        }
        wt[lane] = v;
    }
    __syncthreads();
    int woff2 = (wv > 0) ? wt[wv - 1] : 0;
    int run = woff2 + inc3 - cnt4b;
    for (int t = 0; t < 4; ++t) {
        int v = 4 * tid + t;
        relab_g[v] = run;
        if (remb[t]) { perm_a[run] = v; ++run; }
        rem_g[v] = remb[t];
    }
    if (tid == 1023) nkeep_g[0] = run;
}

// ---- kC: all outputs; x region is pure atomic-add over zeroed base ----
__global__ void kC_outputs(const float* __restrict__ x, const int* __restrict__ map_g,
                           const int* __restrict__ rem_g, const int* __restrict__ relab_g,
                           const int* __restrict__ perm_a, const int* __restrict__ ei,
                           const int* __restrict__ batch, const int* __restrict__ nkeep_g,
                           float* __restrict__ out) {
    int idx = blockIdx.x * blockDim.x + threadIdx.x;
    if (idx < NN * ND) {
        int n = idx >> 6, d = idx & 63;
        int m = map_g[n];                 // m==n for centers & kept free nodes
        if (rem_g[m]) atomicAdd(&out[relab_g[m] * ND + d], x[idx]);
    } else if (idx < NN * ND + 2 * NE) {
        int e = idx - NN * ND;
        int row = e >> 16;                // NE == 1<<16
        int ee = e & (NE - 1);
        int s = ei[ee], t = ei[NE + ee];
        bool valid = (rem_g[s] != 0) && (rem_g[t] != 0);
        int endp = (row == 0) ? s : t;
        out[idx] = valid ? (float)relab_g[endp] : -1.0f;
    } else if (idx < NN * ND + 2 * NE + NN) {
        int r = idx - (NN * ND + 2 * NE);
        int nk = nkeep_g[0];
        out[idx] = (r < nk) ? (float)batch[perm_a[r]] : -1.0f;
    } else if (idx < NN * ND + 2 * NE + 2 * NN) {
        int r = idx - (NN * ND + 2 * NE + NN);
        int nk = nkeep_g[0];
        out[idx] = (r < nk) ? (float)perm_a[r] : -1.0f;
    }
}

extern "C" void kernel_launch(void* const* d_in, const int* in_sizes, int n_in,
                              void* d_out, int out_size, void* d_ws, size_t ws_size,
                              hipStream_t stream) {
    const float* x     = (const float*)d_in[0];
    const int*   ei    = (const int*)d_in[1];
    const int*   batch = (const int*)d_in[2];
    const float* wrel  = (const float*)d_in[3];
    const float* wroot = (const float*)d_in[4];
    const float* b     = (const float*)d_in[5];

    char* ws = (char*)d_ws;
    double*         srel   = (double*)(ws + 0);              // 32768
    double*         sroot  = (double*)(ws + 32768);          // 32768
    int*            map_g  = (int*)(ws + 65536);             // 16384
    int*            rem_g  = (int*)(ws + 81920);             // 16384
    int*            relab  = (int*)(ws + 98304);             // 16384
    int*            perma  = (int*)(ws + 114688);            // 16384
    int*            nkeep  = (int*)(ws + 131072);            // 128
    int*            gcnt_d = (int*)(ws + 131200);            // 16384
    int*            gcnt_s = (int*)(ws + 147584);            // 16384
    unsigned short* gbuf_d = (unsigned short*)(ws + 163968); // 360448
    unsigned short* gbuf_s = (unsigned short*)(ws + 524416); // 360448

    float* out = (float*)d_out;

    hipMemsetAsync(gcnt_d, 0, 32768, stream);   // zeroes gcnt_d + gcnt_s (adjacent)
    kA_pre<<<256, 256, 0, stream>>>(x, ei, wrel, wroot, srel, sroot, gcnt_d, gcnt_s,
                                    gbuf_d, gbuf_s, out);
    kB_contract<<<1, 1024, 0, stream>>>(srel, sroot, b, gcnt_d, gbuf_d, gcnt_s, gbuf_s,
                                        map_g, rem_g, relab, perma, nkeep);
    int total_out = NN * ND + 2 * NE + 2 * NN;  // 401408
    kC_outputs<<<(total_out + 255) / 256, 256, 0, stream>>>(x, map_g, rem_g, relab,
                                                            perma, ei, batch, nkeep, out);
}

// Round 12
// 203.464 us; speedup vs baseline: 1.5150x; 1.5150x over previous
//
#include <hip/hip_runtime.h>

#define NN 4096
#define NE 65536
#define ND 64
#define BCAP 44   // per-node in-edge bucket capacity (Poisson(16) tail @44 ~ 1e-9)

// ---- kA (256x256): dots + zero x_pooled + bucketed in-edge scatter ----
__global__ void kA_pre(const float* __restrict__ x, const int* __restrict__ ei,
                       const float* __restrict__ wrel, const float* __restrict__ wroot,
                       double* __restrict__ srel, double* __restrict__ sroot,
                       int* __restrict__ gcnt, unsigned short* __restrict__ gbuf,
                       float* __restrict__ out) {
    int gtid = blockIdx.x * blockDim.x + threadIdx.x;   // 65536 threads
    int lane = threadIdx.x & 63;

    float4* o4 = (float4*)out;
    o4[gtid] = make_float4(0.f, 0.f, 0.f, 0.f);         // zero x_pooled base (1 MB)

    int gwave = gtid >> 6;                              // 1024 waves, 4 nodes each
    for (int node = gwave; node < NN; node += 1024) {
        double xv = (double)x[node * ND + lane];
        double pr = xv * (double)wrel[lane];
        double po = xv * (double)wroot[lane];
        for (int off = 32; off > 0; off >>= 1) {
            pr += __shfl_down(pr, off);
            po += __shfl_down(po, off);
        }
        if (lane == 0) { srel[node] = pr; sroot[node] = po; }
    }

    int s = ei[gtid], d = ei[NE + gtid];                // one edge per thread
    int pd = atomicAdd(&gcnt[d], 1);
    if (pd < BCAP) gbuf[d * BCAP + pd] = (unsigned short)s;   // in-edges by dst
}

// ---- kB (1x1024): keys + sorted-row head-walk fixpoint ----
// earlier(u,v) <=> kq(u) < kq(v), kq = (~mono_f32_score)<<12 | node (stable argsort ties).
// skey[node] u64 = kq<<2 | stat (0=unresolved,1=center,2=absorbed).
// Rows <=16 survivors: sorted ascending by key (register bitonic-16); fixpoint polls the
// head only: center -> absorbed by it; absorbed -> advance; unresolved -> stall.
// Rows >16: R10 rescan fallback. Idle threads back off (s_sleep) to keep the LDS pipe
// clear for the sequential resolution chain.
__global__ void __launch_bounds__(1024) kB_contract(
        const double* __restrict__ srel, const double* __restrict__ sroot,
        const float* __restrict__ bptr, const int* __restrict__ gcnt,
        const unsigned short* __restrict__ gbuf,
        int* __restrict__ map_g, int* __restrict__ rem_g, int* __restrict__ relab_g,
        int* __restrict__ perm_a, int* __restrict__ nkeep_g) {
    __shared__ __align__(16) char buf[163840];
    unsigned short* incsr = (unsigned short*)buf;
    char* aux = buf + 131072;
    double* srel_lds = (double*)aux;
    volatile unsigned long long* skey = (volatile unsigned long long*)aux;
    int* wt = (int*)(aux + 20544);
    int tid = threadIdx.x, lane = tid & 63, wv = tid >> 6;

    // ---- prefix of capped in-degrees -> row starts/ends in regs ----
    int4 d4 = ((const int4*)gcnt)[tid];
    int t0 = min(d4.x, BCAP), t1 = min(d4.y, BCAP);
    int t2 = min(d4.z, BCAP), t3 = min(d4.w, BCAP);
    int tot = t0 + t1 + t2 + t3;
    int inc = tot;
    for (int off = 1; off < 64; off <<= 1) {
        int v = __shfl_up(inc, off);
        if (lane >= off) inc += v;
    }
    if (lane == 63) wt[wv] = inc;
    __syncthreads();
    if (wv == 0 && lane < 16) {
        int v = wt[lane];
        for (int off = 1; off < 16; off <<= 1) {
            int u2 = __shfl_up(v, off);
            if (lane >= off) v += u2;
        }
        wt[lane] = v;
    }
    __syncthreads();
    int waveoff = (wv > 0) ? wt[wv - 1] : 0;
    int excl = waveoff + inc - tot;
    int rs4[4], re4[4];
    rs4[0] = excl; rs4[1] = excl + t0; rs4[2] = excl + t0 + t1; rs4[3] = excl + t0 + t1 + t2;
    re4[0] = rs4[1]; re4[1] = rs4[2]; re4[2] = rs4[3]; re4[3] = rs4[3] + t3;
    __syncthreads();   // wt reads done before srel staging overwrites aux

    // ---- gather bucket rows global -> compact LDS in-CSR ----
    for (int t = 0; t < 4; ++t) {
        int v = 4 * tid + t;
        const unsigned short* gp = gbuf + v * BCAP;
        int base = rs4[t], dg = re4[t] - rs4[t];
        int j = 0;
        for (; j + 4 <= dg; j += 4) {
            ushort4 q = *(const ushort4*)(gp + j);
            incsr[base + j] = q.x; incsr[base + j + 1] = q.y;
            incsr[base + j + 2] = q.z; incsr[base + j + 3] = q.w;
        }
        for (; j < dg; ++j) incsr[base + j] = gp[j];
    }

    // ---- stage srel into LDS ----
    {
        double2* sl2 = (double2*)aux;
        const double2* sg2 = (const double2*)srel;
        for (int i = tid; i < NN / 2; i += 1024) sl2[i] = sg2[i];
    }
    __syncthreads();

    // ---- agg row-gather + key computation (regs only) ----
    double bv = (double)bptr[0];
    unsigned long long pk4[4];
    for (int t = 0; t < 4; ++t) {
        int v = 4 * tid + t;
        double s = 0.0;
        for (int e = rs4[t]; e < re4[t]; ++e) s += srel_lds[(int)incsr[e]];
        double arg = s + sroot[v] + bv;
        float sc = tanhf((float)arg);                    // f32 saturation => ref ties
        unsigned m = __float_as_uint(sc);
        m = (m & 0x80000000u) ? ~m : (m | 0x80000000u);  // monotone ascending
        pk4[t] = ((unsigned long long)(~m) << 12) | (unsigned long long)v;   // kq
    }
    __syncthreads();   // srel_lds reads done before skey overwrites region

    for (int t = 0; t < 4; ++t) skey[4 * tid + t] = pk4[t] << 2;
    __syncthreads();

    // ---- round 0: prune rows to earlier-only; sort small rows in registers ----
    unsigned long long minC4[4];
    int ptr4[4], uh4[4];
    unsigned resolved = 0, centerm = 0, selfm = 0, walkm = 0;
    for (int t = 0; t < 4; ++t) {
        int v = 4 * tid + t;
        unsigned long long pkv = pk4[t];
        minC4[t] = ~0ULL;
        int w = rs4[t];
        for (int e = rs4[t]; e < re4[t]; ++e) {
            int u = (int)incsr[e];
            if (u == v) { selfm |= 1u << t; continue; }
            if ((skey[u] >> 2) < pkv) incsr[w++] = (unsigned short)u;
        }
        re4[t] = w;
        int m = w - rs4[t];
        if (m == 0) {                                    // no earlier in-nbrs: center
            map_g[v] = v;
            skey[v] = (pkv << 2) | 1ULL;
            centerm |= 1u << t; resolved |= 1u << t;
        } else if (m <= 16) {                            // register bitonic sort by key
            walkm |= 1u << t;
            unsigned long long kk[16];
            int base = rs4[t];
#pragma unroll
            for (int j = 0; j < 16; ++j)
                kk[j] = (j < m) ? (skey[(int)incsr[base + j]] & ~3ULL) : ~0ULL;
#pragma unroll
            for (int k2 = 2; k2 <= 16; k2 <<= 1) {
#pragma unroll
                for (int j2 = k2 >> 1; j2 > 0; j2 >>= 1) {
#pragma unroll
                    for (int i2 = 0; i2 < 16; ++i2) {
                        int l2 = i2 ^ j2;
                        if (l2 > i2) {
                            bool up = ((i2 & k2) == 0);
                            if ((kk[i2] > kk[l2]) == up) {
                                unsigned long long tmp = kk[i2];
                                kk[i2] = kk[l2]; kk[l2] = tmp;
                            }
                        }
                    }
                }
            }
#pragma unroll
            for (int j = 0; j < 16; ++j)
                if (j < m) incsr[base + j] = (unsigned short)((kk[j] >> 2) & 0xFFFULL);
            ptr4[t] = base;
            uh4[t] = (int)((kk[0] >> 2) & 0xFFFULL);
        }
        // m > 16: fallback rescan mode (row stays unsorted)
    }

    // ---- head-walk / rescan fixpoint ----
    int guard = 0, idle = 0;
    while (resolved != 0xFu && guard < 1000000) {
        ++guard;
        bool prog = false;
        for (int t = 0; t < 4; ++t) {
            if (resolved & (1u << t)) continue;
            int v = 4 * tid + t;
            if (walkm & (1u << t)) {
                unsigned long long sk = skey[uh4[t]];
                int st = (int)(sk & 3ULL);
                if (st == 1) {                        // head center = min-key absorber
                    map_g[v] = (int)((sk >> 2) & 0xFFFULL);
                    skey[v] = (pk4[t] << 2) | 2ULL;
                    resolved |= 1u << t; prog = true;
                } else if (st == 2) {                 // head absorbed: advance
                    int p = ptr4[t] + 1, end = re4[t];
                    int u = -1; unsigned long long s2 = 0;
                    while (p < end) {
                        u = (int)incsr[p];
                        s2 = skey[u];
                        if ((s2 & 3ULL) == 2ULL) { ++p; continue; }
                        break;
                    }
                    if (p >= end) {                   // all absorbed: center
                        map_g[v] = v;
                        skey[v] = (pk4[t] << 2) | 1ULL;
                        centerm |= 1u << t; resolved |= 1u << t;
                    } else {
                        ptr4[t] = p; uh4[t] = u;
                        if ((s2 & 3ULL) == 1ULL) {    // landed on a center
                            map_g[v] = (int)((s2 >> 2) & 0xFFFULL);
                            skey[v] = (pk4[t] << 2) | 2ULL;
                            resolved |= 1u << t;
                        }
                    }
                    prog = true;
                }
                // st==0: stall
            } else {
                // fallback: R10 rescan with compaction
                int lo = rs4[t], hi = re4[t];
                unsigned long long minU = ~0ULL, mC = minC4[t];
                int w = lo;
                for (int e = lo; e < hi; ++e) {
                    int u = (int)incsr[e];
                    unsigned long long sk = skey[u];
                    int st = (int)(sk & 3ULL);
                    unsigned long long ku = sk >> 2;
                    if (st == 0) { incsr[w++] = (unsigned short)u; if (ku < minU) minU = ku; }
                    else if (st == 1) { if (ku < mC) mC = ku; }
                }
                if (w != hi) prog = true;
                re4[t] = w; minC4[t] = mC;
                if (mC < minU) {
                    map_g[v] = (int)(mC & 0xFFFULL);
                    skey[v] = (pk4[t] << 2) | 2ULL;
                    resolved |= 1u << t; prog = true;
                } else if (w == lo) {
                    map_g[v] = v;
                    skey[v] = (pk4[t] << 2) | 1ULL;
                    centerm |= 1u << t; resolved |= 1u << t; prog = true;
                }
            }
        }
        if (!prog) {
            if (((++idle) & 3) == 0) __builtin_amdgcn_s_sleep(1);
        } else idle = 0;
    }
    __syncthreads();

    // ---- relabel prefix + perm + globals ----
    int remb[4], cnt4b = 0;
    for (int t = 0; t < 4; ++t) {
        remb[t] = ((centerm >> t) & 1) && !((selfm >> t) & 1);
        cnt4b += remb[t];
    }
    int inc3 = cnt4b;
    for (int off = 1; off < 64; off <<= 1) {
        int v = __shfl_up(inc3, off);
        if (lane >= off) inc3 += v;
    }
    if (lane == 63) wt[wv] = inc3;
    __syncthreads();
    if (wv == 0 && lane < 16) {
        int v = wt[lane];
        for (int off = 1; off < 16; off <<= 1) {
            int u2 = __shfl_up(v, off);
            if (lane >= off) v += u2;
        }
        wt[lane] = v;
    }
    __syncthreads();
    int woff2 = (wv > 0) ? wt[wv - 1] : 0;
    int run = woff2 + inc3 - cnt4b;
    for (int t = 0; t < 4; ++t) {
        int v = 4 * tid + t;
        relab_g[v] = run;
        if (remb[t]) { perm_a[run] = v; ++run; }
        rem_g[v] = remb[t];
    }
    if (tid == 1023) nkeep_g[0] = run;
}

// ---- kC: all outputs; x region is pure atomic-add over zeroed base ----
__global__ void kC_outputs(const float* __restrict__ x, const int* __restrict__ map_g,
                           const int* __restrict__ rem_g, const int* __restrict__ relab_g,
                           const int* __restrict__ perm_a, const int* __restrict__ ei,
                           const int* __restrict__ batch, const int* __restrict__ nkeep_g,
                           float* __restrict__ out) {
    int idx = blockIdx.x * blockDim.x + threadIdx.x;
    if (idx < NN * ND) {
        int n = idx >> 6, d = idx & 63;
        int m = map_g[n];                 // m==n for centers & kept free nodes
        if (rem_g[m]) atomicAdd(&out[relab_g[m] * ND + d], x[idx]);
    } else if (idx < NN * ND + 2 * NE) {
        int e = idx - NN * ND;
        int row = e >> 16;                // NE == 1<<16
        int ee = e & (NE - 1);
        int s = ei[ee], t = ei[NE + ee];
        bool valid = (rem_g[s] != 0) && (rem_g[t] != 0);
        int endp = (row == 0) ? s : t;
        out[idx] = valid ? (float)relab_g[endp] : -1.0f;
    } else if (idx < NN * ND + 2 * NE + NN) {
        int r = idx - (NN * ND + 2 * NE);
        int nk = nkeep_g[0];
        out[idx] = (r < nk) ? (float)batch[perm_a[r]] : -1.0f;
    } else if (idx < NN * ND + 2 * NE + 2 * NN) {
        int r = idx - (NN * ND + 2 * NE + NN);
        int nk = nkeep_g[0];
        out[idx] = (r < nk) ? (float)perm_a[r] : -1.0f;
    }
}

extern "C" void kernel_launch(void* const* d_in, const int* in_sizes, int n_in,
                              void* d_out, int out_size, void* d_ws, size_t ws_size,
                              hipStream_t stream) {
    const float* x     = (const float*)d_in[0];
    const int*   ei    = (const int*)d_in[1];
    const int*   batch = (const int*)d_in[2];
    const float* wrel  = (const float*)d_in[3];
    const float* wroot = (const float*)d_in[4];
    const float* b     = (const float*)d_in[5];

    char* ws = (char*)d_ws;
    double*         srel  = (double*)(ws + 0);              // 32768
    double*         sroot = (double*)(ws + 32768);          // 32768
    int*            map_g = (int*)(ws + 65536);             // 16384
    int*            rem_g = (int*)(ws + 81920);             // 16384
    int*            relab = (int*)(ws + 98304);             // 16384
    int*            perma = (int*)(ws + 114688);            // 16384
    int*            nkeep = (int*)(ws + 131072);            // 128
    int*            gcnt  = (int*)(ws + 131200);            // 16384
    unsigned short* gbuf  = (unsigned short*)(ws + 147584); // 360448

    float* out = (float*)d_out;

    hipMemsetAsync(gcnt, 0, NN * sizeof(int), stream);
    kA_pre<<<256, 256, 0, stream>>>(x, ei, wrel, wroot, srel, sroot, gcnt, gbuf, out);
    kB_contract<<<1, 1024, 0, stream>>>(srel, sroot, b, gcnt, gbuf, map_g, rem_g,
                                        relab, perma, nkeep);
    int total_out = NN * ND + 2 * NE + 2 * NN;  // 401408
    kC_outputs<<<(total_out + 255) / 256, 256, 0, stream>>>(x, map_g, rem_g, relab,
                                                            perma, ei, batch, nkeep, out);
}